// Round 6
// baseline (392.518 us; speedup 1.0000x reference)
//
#include <hip/hip_runtime.h>
#include <hip/hip_bf16.h>
#include <math.h>

#define N_PIX 4096
#define CCH 32
#define BB 2

typedef __attribute__((ext_vector_type(8))) short short8;
typedef __attribute__((ext_vector_type(4))) float f32x4;

// ---------------------------------------------------------------------------
// Conv 3x3 SAME + bias + ReLU, Cout=32 fixed, fp32.
// Block = one (batch,row) for one weight-set (blockIdx.y selects among 3).
// 256 threads: px = t&63 (column), g = wave id (readfirstlane-forced uniform)
// selects 8 output channels. Weights are read via SGPR scalar loads
// (wave-uniform index) -> no LDS weight staging, no ds_read_b128 in the
// inner loop; FMAs take the weight as an SGPR operand.
// ---------------------------------------------------------------------------
struct ConvArgs {
  const float* in0[3];
  const float* in1[3];   // optional second input (concat), may be null
  const float* w[3];
  const float* bias[3];
  float* out[3];
  int cin0, cin1;
};

__global__ __launch_bounds__(256) void conv3_relu(ConvArgs a)
{
  const int sel = blockIdx.y;
  const int b = blockIdx.x >> 6;
  const int y = blockIdx.x & 63;
  const float* __restrict__ in0  = a.in0[sel];
  const float* __restrict__ in1  = a.in1[sel];
  const float* __restrict__ w    = a.w[sel];
  const float* __restrict__ bias = a.bias[sel];
  float* __restrict__ out        = a.out[sel];
  const int cin0 = a.cin0, cin1 = a.cin1, cinT = cin0 + cin1;

  __shared__ __align__(16) float xs[16*3*66];   // [ci][r][col(66, zero-padded)]

  const int t  = threadIdx.x;
  const int px = t & 63;
  // wave index -> uniform: enables scalar (s_load) weight reads
  const int g   = __builtin_amdgcn_readfirstlane(t >> 6);
  const int co0 = g * 8;

  float acc[8] = {0.f,0.f,0.f,0.f,0.f,0.f,0.f,0.f};

  for (int cb = 0; cb < cinT; cb += 16) {
    // stage input chunk (rows y-1..y+1, cols padded)
    for (int j = t; j < 16*3*66; j += 256) {
      int ci  = j / 198;
      int rem = j - ci*198;
      int r   = rem / 66;
      int col = rem - r*66;
      int yy = y + r - 1;
      int xx = col - 1;
      float vv = 0.f;
      if ((unsigned)yy < 64u && (unsigned)xx < 64u) {
        int ch = cb + ci;
        vv = (ch < cin0)
           ? in0[((size_t)(b*cin0 + ch)*64 + yy)*64 + xx]
           : in1[((size_t)(b*cin1 + (ch-cin0))*64 + yy)*64 + xx];
      }
      xs[j] = vv;
    }
    __syncthreads();
    #pragma unroll 4
    for (int ci = 0; ci < 16; ++ci) {
      float xv[9];
      #pragma unroll
      for (int r = 0; r < 3; ++r)
        #pragma unroll
        for (int kx = 0; kx < 3; ++kx)
          xv[r*3+kx] = xs[(ci*3+r)*66 + px + kx];
      // wave-uniform weight rows -> scalar loads
      const float* wrow = w + ((size_t)co0*cinT + (cb + ci))*9;
      #pragma unroll
      for (int j = 0; j < 8; ++j) {
        const float* wj = wrow + (size_t)j*cinT*9;
        #pragma unroll
        for (int kk = 0; kk < 9; ++kk)
          acc[j] += xv[kk] * wj[kk];
      }
    }
    __syncthreads();
  }
  #pragma unroll
  for (int j = 0; j < 8; ++j) {
    float r = acc[j] + bias[co0 + j];
    out[((size_t)(b*32 + co0 + j)*64 + y)*64 + px] = fmaxf(r, 0.f);
  }
}

// ---------------------------------------------------------------------------
// Convert q,k,v fp32 [b][32][4096] -> bf16 direct [b][32][4096] AND
// transposed [b][4096][32].
// ---------------------------------------------------------------------------
__global__ __launch_bounds__(256) void cvt_qkv(
    const float* __restrict__ q, const float* __restrict__ k, const float* __restrict__ v,
    __hip_bfloat16* __restrict__ qDb, __hip_bfloat16* __restrict__ kDb, __hip_bfloat16* __restrict__ vDb,
    __hip_bfloat16* __restrict__ qTb, __hip_bfloat16* __restrict__ kTb, __hip_bfloat16* __restrict__ vTb)
{
  const int arr = blockIdx.y, b = blockIdx.z;
  const int n0 = blockIdx.x * 64;
  const float* src = (arr == 0 ? q : arr == 1 ? k : v) + (size_t)b*CCH*N_PIX;
  __hip_bfloat16* dD = (arr == 0 ? qDb : arr == 1 ? kDb : vDb) + (size_t)b*CCH*N_PIX;
  __hip_bfloat16* dT = (arr == 0 ? qTb : arr == 1 ? kTb : vTb) + (size_t)b*CCH*N_PIX;

  __shared__ float ls[32][65];
  const int t = threadIdx.x;
  for (int j = t; j < 2048; j += 256) {
    int c = j >> 6, n = j & 63;
    float vv = src[(size_t)c*N_PIX + n0 + n];
    dD[(size_t)c*N_PIX + n0 + n] = __float2bfloat16(vv);
    ls[c][n] = vv;
  }
  __syncthreads();
  for (int j = t; j < 2048; j += 256) {
    int n = j >> 5, c = j & 31;
    dT[(size_t)(n0 + n)*CCH + c] = __float2bfloat16(ls[c][n]);
  }
}

// ---------------------------------------------------------------------------
// MFMA flash attention pass (bf16 inputs, fp32 accumulate/output), NO online
// max: P = exp2(S*scale*log2e - 20); the constant cancels in the softmax
// ratio and fp32 range makes overflow impossible for |logit| < ~400.
// Row sums accumulate per-lane, reduced once at the end.
// Block = 16 query rows, 4 waves = 4 m-quarters (1024 m each); partials are
// combined by simple addition (no rescale needed without running max).
// blockIdx.x: 16-row block (256 of them); blockIdx.y: pass; blockIdx.z: batch.
// ---------------------------------------------------------------------------
__global__ __launch_bounds__(256) void attn_mfma(
    const __hip_bfloat16* __restrict__ qD, const __hip_bfloat16* __restrict__ kD,
    const __hip_bfloat16* __restrict__ vD,
    const __hip_bfloat16* __restrict__ qT, const __hip_bfloat16* __restrict__ kT,
    const __hip_bfloat16* __restrict__ vT,
    float* __restrict__ oA, float* __restrict__ oB, float* __restrict__ oC)
{
  const int pass = blockIdx.y, b = blockIdx.z;
  const __hip_bfloat16 *XT, *YT, *ZD; float* O;
  if (pass == 0)      { XT = qT; YT = kT; ZD = vD; O = oA; }
  else if (pass == 1) { XT = kT; YT = vT; ZD = qD; O = oB; }
  else                { XT = vT; YT = qT; ZD = kD; O = oC; }
  const size_t boff = (size_t)b * CCH * N_PIX;
  XT += boff; YT += boff; ZD += boff; O += boff;

  const int t = threadIdx.x;
  const int wave = t >> 6, lane = t & 63;
  const int l15 = lane & 15, q4 = lane >> 4;
  const int n0 = blockIdx.x * 16;
  const int mbase = wave * (N_PIX/4);

  // union: Pt (bf16 [4][16][136], 17408 B) then mg (f32 [4][64][12], 12288 B)
  __shared__ __align__(16) char smem_raw[17408];
  auto Pt = reinterpret_cast<__hip_bfloat16 (*)[16][136]>(smem_raw);
  auto mg = reinterpret_cast<float (*)[64][12]>(smem_raw);

  // A fragment for GEMM1: rows n0+l15, k = c = q4*8..q4*8+7 (constant)
  const short8 a_x = *(const short8*)&XT[(size_t)(n0 + l15)*CCH + q4*8];

  f32x4 oacc0 = {0.f,0.f,0.f,0.f}, oacc1 = {0.f,0.f,0.f,0.f};
  float rs[4] = {0.f,0.f,0.f,0.f};
  const float SC2 = 0.17677669529663687f * 1.4426950408889634f;  // 32^-0.5 * log2(e)
  const float OFF = 20.0f;
  const f32x4 zf = {0.f,0.f,0.f,0.f};

  for (int m0 = mbase; m0 < mbase + N_PIX/4; m0 += 128) {
    // ---- GEMM1: S tile [16 i][128 m] ----
    f32x4 s[8];
    #pragma unroll
    for (int ml = 0; ml < 8; ++ml) {
      const short8 b_y = *(const short8*)&YT[(size_t)(m0 + ml*16 + l15)*CCH + q4*8];
      s[ml] = __builtin_amdgcn_mfma_f32_16x16x32_bf16(a_x, b_y, zf, 0, 0, 0);
    }
    // ---- P = exp2(s*SC2 - OFF), accumulate row sums, write bf16 to LDS ----
    #pragma unroll
    for (int ml = 0; ml < 8; ++ml) {
      #pragma unroll
      for (int r = 0; r < 4; ++r) {
        float p = exp2f(s[ml][r]*SC2 - OFF);
        rs[r] += p;
        Pt[wave][q4*4 + r][ml*16 + l15] = __float2bfloat16(p);
      }
    }
    // ---- GEMM2: O[i][c] += P[i][m] * Z[c][m] ----
    #pragma unroll
    for (int km = 0; km < 4; ++km) {
      const short8 a_p  = *(const short8*)&Pt[wave][l15][km*32 + q4*8];
      const short8 b_z0 = *(const short8*)&ZD[(size_t)l15*N_PIX        + m0 + km*32 + q4*8];
      const short8 b_z1 = *(const short8*)&ZD[(size_t)(16 + l15)*N_PIX + m0 + km*32 + q4*8];
      oacc0 = __builtin_amdgcn_mfma_f32_16x16x32_bf16(a_p, b_z0, oacc0, 0, 0, 0);
      oacc1 = __builtin_amdgcn_mfma_f32_16x16x32_bf16(a_p, b_z1, oacc1, 0, 0, 0);
    }
  }

  // ---- reduce row sums across the 16 lanes of each l15 group ----
  #pragma unroll
  for (int r = 0; r < 4; ++r) {
    float v = rs[r];
    v += __shfl_xor(v, 1);
    v += __shfl_xor(v, 2);
    v += __shfl_xor(v, 4);
    v += __shfl_xor(v, 8);
    rs[r] = v;
  }

  // ---- merge the 4 m-quarters: simple sums (no max -> no rescale) ----
  __syncthreads();   // all waves done reading Pt before overlaying with mg
  #pragma unroll
  for (int r = 0; r < 4; ++r) {
    mg[wave][lane][r]     = oacc0[r];
    mg[wave][lane][4 + r] = oacc1[r];
    mg[wave][lane][8 + r] = rs[r];
  }
  __syncthreads();
  if (wave == 0) {
    #pragma unroll
    for (int r = 0; r < 4; ++r) {
      float dn = mg[0][lane][8+r] + mg[1][lane][8+r] + mg[2][lane][8+r] + mg[3][lane][8+r];
      float inv = 1.0f / dn;
      float a0 = mg[0][lane][r]   + mg[1][lane][r]   + mg[2][lane][r]   + mg[3][lane][r];
      float a1 = mg[0][lane][4+r] + mg[1][lane][4+r] + mg[2][lane][4+r] + mg[3][lane][4+r];
      O[(size_t)l15*N_PIX        + n0 + q4*4 + r] = a0 * inv;
      O[(size_t)(16 + l15)*N_PIX + n0 + q4*4 + r] = a1 * inv;
    }
  }
}

// ---------------------------------------------------------------------------
__global__ void avg3_k(const float* __restrict__ a, const float* __restrict__ b,
                       const float* __restrict__ c, float* __restrict__ o, int n)
{
  int i = blockIdx.x * 256 + threadIdx.x;
  if (i < n) o[i] = (a[i] + b[i] + c[i]) * (1.0f/3.0f);
}

// ---------------------------------------------------------------------------
extern "C" void kernel_launch(void* const* d_in, const int* in_sizes, int n_in,
                              void* d_out, int out_size, void* d_ws, size_t ws_size,
                              hipStream_t stream)
{
  const float* x   = (const float*)d_in[0];
  const float* wq1 = (const float*)d_in[1];  const float* bq1 = (const float*)d_in[2];
  const float* wq2 = (const float*)d_in[3];  const float* bq2 = (const float*)d_in[4];
  const float* wk1 = (const float*)d_in[5];  const float* bk1 = (const float*)d_in[6];
  const float* wk2 = (const float*)d_in[7];  const float* bk2 = (const float*)d_in[8];
  const float* wv1 = (const float*)d_in[9];  const float* bv1 = (const float*)d_in[10];
  const float* wv2 = (const float*)d_in[11]; const float* bv2 = (const float*)d_in[12];
  const float* wr  = (const float*)d_in[13]; const float* br  = (const float*)d_in[14];
  const float* wg  = (const float*)d_in[15]; const float* bg  = (const float*)d_in[16];
  const float* wb_ = (const float*)d_in[17]; const float* bb_ = (const float*)d_in[18];
  const float* w2  = (const float*)d_in[19]; const float* b2  = (const float*)d_in[20];
  const float* w3  = (const float*)d_in[21]; const float* b3  = (const float*)d_in[22];

  float* ws = (float*)d_ws;
  const size_t SLOT = (size_t)BB * CCH * N_PIX;   // 262144 floats = 1 MB
  float* s0 = ws + 0*SLOT;
  float* s1 = ws + 1*SLOT;
  float* s2 = ws + 2*SLOT;
  float* s3 = ws + 3*SLOT;
  float* s4 = ws + 4*SLOT;
  float* s5 = ws + 5*SLOT;
  float* s6 = ws + 6*SLOT;
  float* s7 = ws + 7*SLOT;
  float* s8 = ws + 8*SLOT;

  // bf16 q/k/v (direct + transposed) overlay slots s6..s8 (free until stage 3)
  __hip_bfloat16* bfbase = (__hip_bfloat16*)s6;
  const size_t BSLOT = SLOT;                       // elements per bf16 array
  __hip_bfloat16* qDb = bfbase + 0*BSLOT;
  __hip_bfloat16* kDb = bfbase + 1*BSLOT;
  __hip_bfloat16* vDb = bfbase + 2*BSLOT;
  __hip_bfloat16* qTb = bfbase + 3*BSLOT;
  __hip_bfloat16* kTb = bfbase + 4*BSLOT;
  __hip_bfloat16* vTb = bfbase + 5*BSLOT;

  // stage 1: x -> q1,k1,v1 (Cin=64)
  ConvArgs a1;
  a1.in0[0]=x; a1.in0[1]=x; a1.in0[2]=x;
  a1.in1[0]=nullptr; a1.in1[1]=nullptr; a1.in1[2]=nullptr;
  a1.w[0]=wq1; a1.w[1]=wk1; a1.w[2]=wv1;
  a1.bias[0]=bq1; a1.bias[1]=bk1; a1.bias[2]=bv1;
  a1.out[0]=s0; a1.out[1]=s1; a1.out[2]=s2;
  a1.cin0=64; a1.cin1=0;
  conv3_relu<<<dim3(BB*64,3), dim3(256), 0, stream>>>(a1);

  // stage 2: -> q,k,v (Cin=32)
  ConvArgs a2;
  a2.in0[0]=s0; a2.in0[1]=s1; a2.in0[2]=s2;
  a2.in1[0]=nullptr; a2.in1[1]=nullptr; a2.in1[2]=nullptr;
  a2.w[0]=wq2; a2.w[1]=wk2; a2.w[2]=wv2;
  a2.bias[0]=bq2; a2.bias[1]=bk2; a2.bias[2]=bv2;
  a2.out[0]=s3; a2.out[1]=s4; a2.out[2]=s5;
  a2.cin0=32; a2.cin1=0;
  conv3_relu<<<dim3(BB*64,3), dim3(256), 0, stream>>>(a2);

  // convert q,k,v to bf16 (direct + transposed)
  cvt_qkv<<<dim3(N_PIX/64, 3, BB), dim3(256), 0, stream>>>(
      s3, s4, s5, qDb, kDb, vDb, qTb, kTb, vTb);

  // attention: 3 passes x 2 batches -> ctx raw into s0,s1,s2
  attn_mfma<<<dim3(N_PIX/16, 3, BB), dim3(256), 0, stream>>>(
      qDb, kDb, vDb, qTb, kTb, vTb, s0, s1, s2);

  // per-pass output convs (Cin=32)  (overwrites bf16 overlay region - done with it)
  ConvArgs a3;
  a3.in0[0]=s0; a3.in0[1]=s1; a3.in0[2]=s2;
  a3.in1[0]=nullptr; a3.in1[1]=nullptr; a3.in1[2]=nullptr;
  a3.w[0]=wr; a3.w[1]=wg; a3.w[2]=wb_;
  a3.bias[0]=br; a3.bias[1]=bg; a3.bias[2]=bb_;
  a3.out[0]=s6; a3.out[1]=s7; a3.out[2]=s8;
  a3.cin0=32; a3.cin1=0;
  conv3_relu<<<dim3(BB*64,3), dim3(256), 0, stream>>>(a3);

  // ctx = (r+g+b)/3 -> s3
  avg3_k<<<dim3((int)(SLOT/256)), dim3(256), 0, stream>>>(s6, s7, s8, s3, (int)SLOT);

  // out = conv(concat(x, ctx), w2)   (Cin = 64 + 32)
  ConvArgs a4;
  a4.in0[0]=x; a4.in0[1]=x; a4.in0[2]=x;
  a4.in1[0]=s3; a4.in1[1]=s3; a4.in1[2]=s3;
  a4.w[0]=w2; a4.w[1]=w2; a4.w[2]=w2;
  a4.bias[0]=b2; a4.bias[1]=b2; a4.bias[2]=b2;
  a4.out[0]=s4; a4.out[1]=s4; a4.out[2]=s4;
  a4.cin0=64; a4.cin1=32;
  conv3_relu<<<dim3(BB*64,1), dim3(256), 0, stream>>>(a4);

  // out = conv(out, w3) -> d_out
  ConvArgs a5;
  a5.in0[0]=s4; a5.in0[1]=s4; a5.in0[2]=s4;
  a5.in1[0]=nullptr; a5.in1[1]=nullptr; a5.in1[2]=nullptr;
  a5.w[0]=w3; a5.w[1]=w3; a5.w[2]=w3;
  a5.bias[0]=b3; a5.bias[1]=b3; a5.bias[2]=b3;
  a5.out[0]=(float*)d_out; a5.out[1]=(float*)d_out; a5.out[2]=(float*)d_out;
  a5.cin0=32; a5.cin1=0;
  conv3_relu<<<dim3(BB*64,1), dim3(256), 0, stream>>>(a5);
}

// Round 7
// 152.528 us; speedup vs baseline: 2.5734x; 2.5734x over previous
//
#include <hip/hip_runtime.h>
#include <hip/hip_bf16.h>
#include <math.h>

#define N_PIX 4096
#define CCH 32
#define BB 2
#define PIX_P 4356   // 66*66 padded pixel grid

typedef __attribute__((ext_vector_type(8))) short short8;
typedef __attribute__((ext_vector_type(4))) float f32x4;

// ---------------------------------------------------------------------------
// Weight convert/reorder: fp32 [co][cin][3][3] -> bf16 [co][kk][ci]
// (K-order (kk,ci) so a k-octet = 8 consecutive input channels at one tap).
// ---------------------------------------------------------------------------
struct WcvtPar {
  const float* src[11];
  int cin[11];
  int dst[11];     // element offset into wbf arena
};

__global__ __launch_bounds__(256) void wcvt_k(WcvtPar p, __hip_bfloat16* __restrict__ wbf)
{
  const int s = blockIdx.y;
  const int cin = p.cin[s];
  const int K = 9*cin;
  const int total = 32*K;
  const float* __restrict__ src = p.src[s];
  __hip_bfloat16* __restrict__ dst = wbf + p.dst[s];
  for (int j = blockIdx.x*256 + threadIdx.x; j < total; j += gridDim.x*256) {
    int co = j / K, k = j - co*K;
    int kk = k / cin, ci = k - kk*cin;
    dst[j] = __float2bfloat16(src[(size_t)(co*cin + ci)*9 + kk]);
  }
}

// ---------------------------------------------------------------------------
// x fp32 NCHW [2][64][64][64] -> bf16 padded pixel-major xcat[b][66*66][96],
// channels 0..63 (64..95 filled later by avg3). Borders pre-zeroed by memset.
// ---------------------------------------------------------------------------
__global__ __launch_bounds__(256) void xpad_k(const float* __restrict__ x,
                                              __hip_bfloat16* __restrict__ xcat)
{
  const int y = blockIdx.x, b = blockIdx.y;
  const int t = threadIdx.x;
  for (int j = t; j < 4096; j += 256) {
    int ci = j >> 6, xx = j & 63;
    float v = x[((size_t)(b*64 + ci)*64 + y)*64 + xx];
    xcat[((size_t)b*PIX_P + (size_t)(y+1)*66 + xx+1)*96 + ci] = __float2bfloat16(v);
  }
}

// ---------------------------------------------------------------------------
// avg3: ctx = (r+g+b)/3, bf16 unpadded pixel-major [2][4096][32] inputs,
// writes xcat channels 64..95 (padded interior).
// ---------------------------------------------------------------------------
__global__ __launch_bounds__(256) void avg3_k(
    const __hip_bfloat16* __restrict__ r, const __hip_bfloat16* __restrict__ g,
    const __hip_bfloat16* __restrict__ bl, __hip_bfloat16* __restrict__ xcat)
{
  const int y = blockIdx.x, b = blockIdx.y;
  const int t = threadIdx.x;
  for (int j = t; j < 64*32; j += 256) {
    int xx = j >> 5, c = j & 31;
    size_t src = ((size_t)b*N_PIX + y*64 + xx)*32 + c;
    float v = (__bfloat162float(r[src]) + __bfloat162float(g[src]) +
               __bfloat162float(bl[src])) * (1.0f/3.0f);
    xcat[((size_t)b*PIX_P + (size_t)(y+1)*66 + xx+1)*96 + 64 + c] = __float2bfloat16(v);
  }
}

// ---------------------------------------------------------------------------
// MFMA implicit-GEMM 3x3 conv + bias + ReLU, Cout=32, bf16 in, fp32 accum.
// Input: padded pixel-major bf16 [66*66][sch]; weights bf16 [32][9*CIN]
// ((kk,ci) order). Block = 1 image row (4 waves x 16 pixels); per 32-k step:
// 1 A-frag (im2col, direct 16B load) + 2 B-frags (weights) -> 2 MFMAs.
// Output modes (bitmask): 1=padded bf16 pixel-major, 2=unpadded bf16
// pixel-major, 4=bf16 channel-major, 8=fp32 channel-major (NCHW).
// ---------------------------------------------------------------------------
struct ConvPar {
  const __hip_bfloat16* in[3];
  const __hip_bfloat16* wb[3];
  const float* bias[3];
  __hip_bfloat16* outPad[3];
  __hip_bfloat16* outPix[3];
  __hip_bfloat16* outCh[3];
  float* outF[3];
  int mode, sch;
};

template<int CIN>
__global__ __launch_bounds__(256) void conv_mfma(ConvPar p)
{
  constexpr int K = 9*CIN;
  const int sel = blockIdx.y, b = blockIdx.z;
  const int sch = p.sch;
  const __hip_bfloat16* __restrict__ in = p.in[sel] + (size_t)b*PIX_P*sch;
  const __hip_bfloat16* __restrict__ wb = p.wb[sel];
  const float* __restrict__ bias = p.bias[sel];
  const int t = threadIdx.x, wave = t >> 6, lane = t & 63;
  const int l15 = lane & 15, q4 = lane >> 4;
  const int y = blockIdx.x;
  const int xw = wave*16;

  f32x4 acc0 = {0.f,0.f,0.f,0.f}, acc1 = {0.f,0.f,0.f,0.f};
  #pragma unroll
  for (int ks = 0; ks < K/32; ++ks) {
    const int kk  = (ks*32)/CIN;           // tap index 0..8 (constant after unroll)
    const int ci0 = (ks*32)%CIN + q4*8;    // input-channel octet
    const int dy = kk/3 - 1, dx = (kk%3) - 1;
    const short8 bw0 = *(const short8*)&wb[(size_t)l15*K      + ks*32 + q4*8];
    const short8 bw1 = *(const short8*)&wb[(size_t)(16+l15)*K + ks*32 + q4*8];
    const short8 av  = *(const short8*)&in[((size_t)(y+1+dy)*66 + xw + l15 + 1 + dx)*sch + ci0];
    acc0 = __builtin_amdgcn_mfma_f32_16x16x32_bf16(av, bw0, acc0, 0, 0, 0);
    acc1 = __builtin_amdgcn_mfma_f32_16x16x32_bf16(av, bw1, acc1, 0, 0, 0);
  }
  // D layout: col(lane&15) = co (B row), row(q4*4+r) = pixel (A row)
  const float bz0 = bias[l15], bz1 = bias[16 + l15];
  #pragma unroll
  for (int r = 0; r < 4; ++r) {
    const int xx = xw + q4*4 + r;
    const int pix = y*64 + xx;
    const float v0 = fmaxf(acc0[r] + bz0, 0.f);
    const float v1 = fmaxf(acc1[r] + bz1, 0.f);
    if (p.mode & 1) {
      __hip_bfloat16* o = p.outPad[sel] + ((size_t)b*PIX_P + (size_t)(y+1)*66 + xx+1)*32;
      o[l15] = __float2bfloat16(v0); o[16+l15] = __float2bfloat16(v1);
    }
    if (p.mode & 2) {
      __hip_bfloat16* o = p.outPix[sel] + ((size_t)b*N_PIX + pix)*32;
      o[l15] = __float2bfloat16(v0); o[16+l15] = __float2bfloat16(v1);
    }
    if (p.mode & 4) {
      __hip_bfloat16* o = p.outCh[sel] + (size_t)b*32*N_PIX + pix;
      o[(size_t)l15*N_PIX]      = __float2bfloat16(v0);
      o[(size_t)(16+l15)*N_PIX] = __float2bfloat16(v1);
    }
    if (p.mode & 8) {
      float* o = p.outF[sel] + (size_t)b*32*N_PIX + pix;
      o[(size_t)l15*N_PIX]      = v0;
      o[(size_t)(16+l15)*N_PIX] = v1;
    }
  }
}

// ---------------------------------------------------------------------------
// MFMA flash attention pass (bf16 in, fp32 accum), no online max (verified
// R6: P = exp2(S*scale*log2e - 20), constant cancels in the ratio).
// Inputs: pixel-major [b][4096][32] (X^T/Y^T operands) + channel-major
// [b][32][4096] (Z operand). Output: bf16 padded pixel-major ctx per pass.
// Block = 16 query rows, 4 waves = 4 m-quarters; merge by simple adds.
// ---------------------------------------------------------------------------
__global__ __launch_bounds__(256) void attn_mfma(
    const __hip_bfloat16* __restrict__ qP, const __hip_bfloat16* __restrict__ kP,
    const __hip_bfloat16* __restrict__ vP,
    const __hip_bfloat16* __restrict__ qC, const __hip_bfloat16* __restrict__ kC,
    const __hip_bfloat16* __restrict__ vC,
    __hip_bfloat16* __restrict__ ctxPad)
{
  const int pass = blockIdx.y, b = blockIdx.z;
  const __hip_bfloat16 *XT, *YT, *ZD;
  if (pass == 0)      { XT = qP; YT = kP; ZD = vC; }
  else if (pass == 1) { XT = kP; YT = vP; ZD = qC; }
  else                { XT = vP; YT = qP; ZD = kC; }
  const size_t boff = (size_t)b * CCH * N_PIX;
  XT += boff; YT += boff; ZD += boff;
  __hip_bfloat16* __restrict__ ctx = ctxPad + ((size_t)(pass*BB + b))*PIX_P*32;

  const int t = threadIdx.x;
  const int wave = t >> 6, lane = t & 63;
  const int l15 = lane & 15, q4 = lane >> 4;
  const int n0 = blockIdx.x * 16;
  const int mbase = wave * (N_PIX/4);

  // union: Pt (bf16 [4][16][136]) then mg (f32 [4][64][12])
  __shared__ __align__(16) char smem_raw[17408];
  auto Pt = reinterpret_cast<__hip_bfloat16 (*)[16][136]>(smem_raw);
  auto mg = reinterpret_cast<float (*)[64][12]>(smem_raw);

  const short8 a_x = *(const short8*)&XT[(size_t)(n0 + l15)*CCH + q4*8];

  f32x4 oacc0 = {0.f,0.f,0.f,0.f}, oacc1 = {0.f,0.f,0.f,0.f};
  float rs[4] = {0.f,0.f,0.f,0.f};
  const float SC2 = 0.17677669529663687f * 1.4426950408889634f;  // 32^-0.5 * log2(e)
  const float OFF = 20.0f;
  const f32x4 zf = {0.f,0.f,0.f,0.f};

  for (int m0 = mbase; m0 < mbase + N_PIX/4; m0 += 128) {
    f32x4 s[8];
    #pragma unroll
    for (int ml = 0; ml < 8; ++ml) {
      const short8 b_y = *(const short8*)&YT[(size_t)(m0 + ml*16 + l15)*CCH + q4*8];
      s[ml] = __builtin_amdgcn_mfma_f32_16x16x32_bf16(a_x, b_y, zf, 0, 0, 0);
    }
    #pragma unroll
    for (int ml = 0; ml < 8; ++ml) {
      #pragma unroll
      for (int r = 0; r < 4; ++r) {
        float pv = exp2f(s[ml][r]*SC2 - OFF);
        rs[r] += pv;
        Pt[wave][q4*4 + r][ml*16 + l15] = __float2bfloat16(pv);
      }
    }
    #pragma unroll
    for (int km = 0; km < 4; ++km) {
      const short8 a_p  = *(const short8*)&Pt[wave][l15][km*32 + q4*8];
      const short8 b_z0 = *(const short8*)&ZD[(size_t)l15*N_PIX        + m0 + km*32 + q4*8];
      const short8 b_z1 = *(const short8*)&ZD[(size_t)(16 + l15)*N_PIX + m0 + km*32 + q4*8];
      oacc0 = __builtin_amdgcn_mfma_f32_16x16x32_bf16(a_p, b_z0, oacc0, 0, 0, 0);
      oacc1 = __builtin_amdgcn_mfma_f32_16x16x32_bf16(a_p, b_z1, oacc1, 0, 0, 0);
    }
  }

  #pragma unroll
  for (int r = 0; r < 4; ++r) {
    float v = rs[r];
    v += __shfl_xor(v, 1);
    v += __shfl_xor(v, 2);
    v += __shfl_xor(v, 4);
    v += __shfl_xor(v, 8);
    rs[r] = v;
  }

  __syncthreads();   // all waves done with Pt before overlaying with mg
  #pragma unroll
  for (int r = 0; r < 4; ++r) {
    mg[wave][lane][r]     = oacc0[r];
    mg[wave][lane][4 + r] = oacc1[r];
    mg[wave][lane][8 + r] = rs[r];
  }
  __syncthreads();
  if (wave == 0) {
    #pragma unroll
    for (int r = 0; r < 4; ++r) {
      float dn = mg[0][lane][8+r] + mg[1][lane][8+r] + mg[2][lane][8+r] + mg[3][lane][8+r];
      float inv = 1.0f / dn;
      float a0 = mg[0][lane][r]   + mg[1][lane][r]   + mg[2][lane][r]   + mg[3][lane][r];
      float a1 = mg[0][lane][4+r] + mg[1][lane][4+r] + mg[2][lane][4+r] + mg[3][lane][4+r];
      int pix = n0 + q4*4 + r;
      int yy = pix >> 6, xx = pix & 63;
      __hip_bfloat16* o = ctx + ((size_t)(yy+1)*66 + xx+1)*32;
      o[l15]      = __float2bfloat16(a0 * inv);
      o[16 + l15] = __float2bfloat16(a1 * inv);
    }
  }
}

// ---------------------------------------------------------------------------
extern "C" void kernel_launch(void* const* d_in, const int* in_sizes, int n_in,
                              void* d_out, int out_size, void* d_ws, size_t ws_size,
                              hipStream_t stream)
{
  const float* x   = (const float*)d_in[0];
  const float* wq1 = (const float*)d_in[1];  const float* bq1 = (const float*)d_in[2];
  const float* wq2 = (const float*)d_in[3];  const float* bq2 = (const float*)d_in[4];
  const float* wk1 = (const float*)d_in[5];  const float* bk1 = (const float*)d_in[6];
  const float* wk2 = (const float*)d_in[7];  const float* bk2 = (const float*)d_in[8];
  const float* wv1 = (const float*)d_in[9];  const float* bv1 = (const float*)d_in[10];
  const float* wv2 = (const float*)d_in[11]; const float* bv2 = (const float*)d_in[12];
  const float* wr  = (const float*)d_in[13]; const float* br  = (const float*)d_in[14];
  const float* wg  = (const float*)d_in[15]; const float* bg  = (const float*)d_in[16];
  const float* wb_ = (const float*)d_in[17]; const float* bb_ = (const float*)d_in[18];
  const float* w2  = (const float*)d_in[19]; const float* b2  = (const float*)d_in[20];
  const float* w3  = (const float*)d_in[21]; const float* b3  = (const float*)d_in[22];

  // ---- workspace layout (bytes) ----
  char* base = (char*)d_ws;
  __hip_bfloat16* xcat  = (__hip_bfloat16*)(base + 0);        // [2][4356][96] padded
  __hip_bfloat16* q1p   = (__hip_bfloat16*)(base + 1672704);  // [3][2][4356][32] padded (later rgb)
  __hip_bfloat16* ctxP  = (__hip_bfloat16*)(base + 3345408);  // [3][2][4356][32] padded
  __hip_bfloat16* out4p = (__hip_bfloat16*)(base + 5018112);  // [2][4356][32] padded
  __hip_bfloat16* qkvP  = (__hip_bfloat16*)(base + 5575680);  // [3][2][4096][32]
  __hip_bfloat16* qkvC  = (__hip_bfloat16*)(base + 7148544);  // [3][2][32][4096]
  __hip_bfloat16* wbf   = (__hip_bfloat16*)(base + 8721408);  // 147456 elems
  const size_t PADSLOT = (size_t)BB*PIX_P*32;                 // 278784 elems
  const size_t UPSLOT  = (size_t)BB*N_PIX*32;                 // 262144 elems

  // zero all padded buffers (borders must be 0 every call)
  hipMemsetAsync(d_ws, 0, 5575680, stream);

  // weight convert/reorder + x padding
  WcvtPar wp;
  const float* wsrc[11] = {wq1,wk1,wv1,wq2,wk2,wv2,wr,wg,wb_,w2,w3};
  const int    wcin[11] = {64,64,64,32,32,32,32,32,32,96,32};
  const int    wdst[11] = {0,18432,36864,55296,64512,73728,82944,92160,101376,110592,138240};
  for (int i = 0; i < 11; ++i) { wp.src[i]=wsrc[i]; wp.cin[i]=wcin[i]; wp.dst[i]=wdst[i]; }
  wcvt_k<<<dim3(108, 11), dim3(256), 0, stream>>>(wp, wbf);
  xpad_k<<<dim3(64, BB), dim3(256), 0, stream>>>(x, xcat);

  // a1: xcat(ch 0..63) -> q1p/k1p/v1p (padded bf16)
  ConvPar c1 = {};
  for (int i = 0; i < 3; ++i) c1.in[i] = xcat;
  c1.wb[0]=wbf+0; c1.wb[1]=wbf+18432; c1.wb[2]=wbf+36864;
  c1.bias[0]=bq1; c1.bias[1]=bk1; c1.bias[2]=bv1;
  c1.outPad[0]=q1p; c1.outPad[1]=q1p+PADSLOT; c1.outPad[2]=q1p+2*PADSLOT;
  c1.mode = 1; c1.sch = 96;
  conv_mfma<64><<<dim3(64, 3, BB), dim3(256), 0, stream>>>(c1);

  // a2: q1p -> q/k/v in BOTH layouts (pixel-major + channel-major)
  ConvPar c2 = {};
  c2.in[0]=q1p; c2.in[1]=q1p+PADSLOT; c2.in[2]=q1p+2*PADSLOT;
  c2.wb[0]=wbf+55296; c2.wb[1]=wbf+64512; c2.wb[2]=wbf+73728;
  c2.bias[0]=bq2; c2.bias[1]=bk2; c2.bias[2]=bv2;
  c2.outPix[0]=qkvP; c2.outPix[1]=qkvP+UPSLOT; c2.outPix[2]=qkvP+2*UPSLOT;
  c2.outCh[0]=qkvC;  c2.outCh[1]=qkvC+UPSLOT;  c2.outCh[2]=qkvC+2*UPSLOT;
  c2.mode = 6; c2.sch = 32;
  conv_mfma<32><<<dim3(64, 3, BB), dim3(256), 0, stream>>>(c2);

  // attention: 3 passes x 2 batches -> ctxP (padded bf16)
  attn_mfma<<<dim3(N_PIX/16, 3, BB), dim3(256), 0, stream>>>(
      qkvP, qkvP+UPSLOT, qkvP+2*UPSLOT, qkvC, qkvC+UPSLOT, qkvC+2*UPSLOT, ctxP);

  // a3: ctxP -> r/g/b (unpadded bf16 pixel-major, overlaid on q1p region)
  __hip_bfloat16* rgb = q1p;
  ConvPar c3 = {};
  c3.in[0]=ctxP; c3.in[1]=ctxP+PADSLOT; c3.in[2]=ctxP+2*PADSLOT;
  c3.wb[0]=wbf+82944; c3.wb[1]=wbf+92160; c3.wb[2]=wbf+101376;
  c3.bias[0]=br; c3.bias[1]=bg; c3.bias[2]=bb_;
  c3.outPix[0]=rgb; c3.outPix[1]=rgb+UPSLOT; c3.outPix[2]=rgb+2*UPSLOT;
  c3.mode = 2; c3.sch = 32;
  conv_mfma<32><<<dim3(64, 3, BB), dim3(256), 0, stream>>>(c3);

  // ctx average -> xcat channels 64..95
  avg3_k<<<dim3(64, BB), dim3(256), 0, stream>>>(rgb, rgb+UPSLOT, rgb+2*UPSLOT, xcat);

  // a4: xcat (96 ch) -> out4p (padded bf16)
  ConvPar c4 = {};
  c4.in[0]=xcat; c4.wb[0]=wbf+110592; c4.bias[0]=b2;
  c4.outPad[0]=out4p; c4.mode = 1; c4.sch = 96;
  conv_mfma<96><<<dim3(64, 1, BB), dim3(256), 0, stream>>>(c4);

  // a5: out4p -> d_out (fp32 NCHW)
  ConvPar c5 = {};
  c5.in[0]=out4p; c5.wb[0]=wbf+138240; c5.bias[0]=b3;
  c5.outF[0]=(float*)d_out; c5.mode = 8; c5.sch = 32;
  conv_mfma<32><<<dim3(64, 1, BB), dim3(256), 0, stream>>>(c5);
}

// Round 8
// 110.102 us; speedup vs baseline: 3.5651x; 1.3853x over previous
//
#include <hip/hip_runtime.h>
#include <hip/hip_bf16.h>
#include <math.h>

#define N_PIX 4096
#define CCH 32
#define BB 2
#define PIX_P 4356   // 66*66 padded pixel grid

typedef __attribute__((ext_vector_type(8))) short short8;
typedef __attribute__((ext_vector_type(4))) float f32x4;
typedef __attribute__((ext_vector_type(16))) float f32x16;

// ---------------------------------------------------------------------------
// Weight convert/reorder: fp32 [co][cin][3][3] -> bf16 [co][kk][ci]
// ---------------------------------------------------------------------------
struct WcvtPar {
  const float* src[11];
  int cin[11];
  int dst[11];     // element offset into wbf arena
};

__global__ __launch_bounds__(256) void wcvt_k(WcvtPar p, __hip_bfloat16* __restrict__ wbf)
{
  const int s = blockIdx.y;
  const int cin = p.cin[s];
  const int K = 9*cin;
  const int total = 32*K;
  const float* __restrict__ src = p.src[s];
  __hip_bfloat16* __restrict__ dst = wbf + p.dst[s];
  for (int j = blockIdx.x*256 + threadIdx.x; j < total; j += gridDim.x*256) {
    int co = j / K, k = j - co*K;
    int kk = k / cin, ci = k - kk*cin;
    dst[j] = __float2bfloat16(src[(size_t)(co*cin + ci)*9 + kk]);
  }
}

// ---------------------------------------------------------------------------
// x fp32 NCHW -> bf16 padded pixel-major xcat[b][66*66][96], channels 0..63.
// ---------------------------------------------------------------------------
__global__ __launch_bounds__(256) void xpad_k(const float* __restrict__ x,
                                              __hip_bfloat16* __restrict__ xcat)
{
  const int y = blockIdx.x, b = blockIdx.y;
  const int t = threadIdx.x;
  for (int j = t; j < 4096; j += 256) {
    int ci = j >> 6, xx = j & 63;
    float v = x[((size_t)(b*64 + ci)*64 + y)*64 + xx];
    xcat[((size_t)b*PIX_P + (size_t)(y+1)*66 + xx+1)*96 + ci] = __float2bfloat16(v);
  }
}

// ---------------------------------------------------------------------------
// avg3: ctx = (r+g+b)/3 -> xcat channels 64..95 (padded interior).
// ---------------------------------------------------------------------------
__global__ __launch_bounds__(256) void avg3_k(
    const __hip_bfloat16* __restrict__ r, const __hip_bfloat16* __restrict__ g,
    const __hip_bfloat16* __restrict__ bl, __hip_bfloat16* __restrict__ xcat)
{
  const int y = blockIdx.x, b = blockIdx.y;
  const int t = threadIdx.x;
  for (int j = t; j < 64*32; j += 256) {
    int xx = j >> 5, c = j & 31;
    size_t src = ((size_t)b*N_PIX + y*64 + xx)*32 + c;
    float v = (__bfloat162float(r[src]) + __bfloat162float(g[src]) +
               __bfloat162float(bl[src])) * (1.0f/3.0f);
    xcat[((size_t)b*PIX_P + (size_t)(y+1)*66 + xx+1)*96 + 64 + c] = __float2bfloat16(v);
  }
}

// ---------------------------------------------------------------------------
// MFMA implicit-GEMM 3x3 conv + bias + ReLU (unchanged from R7 - verified).
// ---------------------------------------------------------------------------
struct ConvPar {
  const __hip_bfloat16* in[3];
  const __hip_bfloat16* wb[3];
  const float* bias[3];
  __hip_bfloat16* outPad[3];
  __hip_bfloat16* outPix[3];
  __hip_bfloat16* outCh[3];
  float* outF[3];
  int mode, sch;
};

template<int CIN>
__global__ __launch_bounds__(256) void conv_mfma(ConvPar p)
{
  constexpr int K = 9*CIN;
  const int sel = blockIdx.y, b = blockIdx.z;
  const int sch = p.sch;
  const __hip_bfloat16* __restrict__ in = p.in[sel] + (size_t)b*PIX_P*sch;
  const __hip_bfloat16* __restrict__ wb = p.wb[sel];
  const float* __restrict__ bias = p.bias[sel];
  const int t = threadIdx.x, wave = t >> 6, lane = t & 63;
  const int l15 = lane & 15, q4 = lane >> 4;
  const int y = blockIdx.x;
  const int xw = wave*16;

  f32x4 acc0 = {0.f,0.f,0.f,0.f}, acc1 = {0.f,0.f,0.f,0.f};
  #pragma unroll
  for (int ks = 0; ks < K/32; ++ks) {
    const int kk  = (ks*32)/CIN;
    const int ci0 = (ks*32)%CIN + q4*8;
    const int dy = kk/3 - 1, dx = (kk%3) - 1;
    const short8 bw0 = *(const short8*)&wb[(size_t)l15*K      + ks*32 + q4*8];
    const short8 bw1 = *(const short8*)&wb[(size_t)(16+l15)*K + ks*32 + q4*8];
    const short8 av  = *(const short8*)&in[((size_t)(y+1+dy)*66 + xw + l15 + 1 + dx)*sch + ci0];
    acc0 = __builtin_amdgcn_mfma_f32_16x16x32_bf16(av, bw0, acc0, 0, 0, 0);
    acc1 = __builtin_amdgcn_mfma_f32_16x16x32_bf16(av, bw1, acc1, 0, 0, 0);
  }
  const float bz0 = bias[l15], bz1 = bias[16 + l15];
  #pragma unroll
  for (int r = 0; r < 4; ++r) {
    const int xx = xw + q4*4 + r;
    const int pix = y*64 + xx;
    const float v0 = fmaxf(acc0[r] + bz0, 0.f);
    const float v1 = fmaxf(acc1[r] + bz1, 0.f);
    if (p.mode & 1) {
      __hip_bfloat16* o = p.outPad[sel] + ((size_t)b*PIX_P + (size_t)(y+1)*66 + xx+1)*32;
      o[l15] = __float2bfloat16(v0); o[16+l15] = __float2bfloat16(v1);
    }
    if (p.mode & 2) {
      __hip_bfloat16* o = p.outPix[sel] + ((size_t)b*N_PIX + pix)*32;
      o[l15] = __float2bfloat16(v0); o[16+l15] = __float2bfloat16(v1);
    }
    if (p.mode & 4) {
      __hip_bfloat16* o = p.outCh[sel] + (size_t)b*32*N_PIX + pix;
      o[(size_t)l15*N_PIX]      = __float2bfloat16(v0);
      o[(size_t)(16+l15)*N_PIX] = __float2bfloat16(v1);
    }
    if (p.mode & 8) {
      float* o = p.outF[sel] + (size_t)b*32*N_PIX + pix;
      o[(size_t)l15*N_PIX]      = v0;
      o[(size_t)(16+l15)*N_PIX] = v1;
    }
  }
}

// ---------------------------------------------------------------------------
// Attention pass, 32x32x16 MFMA, fully in-register P (no LDS in main loop).
// GEMM1 (swapped operands): S = mfma(A=Y-rows, B=X-cols)
//   -> D col = query i = lane&31, row m = (reg&3) + 8*(reg>>2) + 4*(lane>>5).
// P = exp2(S*scale*log2e - 20) (no online max; verified R6/R7).
// cvt_pk pairs (consecutive m) -> 8 u32 words; 4 x v_permlane32_swap_b32
// regroups them into the two GEMM2 A-fragments (row = i = lane&31,
// k-octet = (lane>>5)*8). GEMM2: O += mfma(A=P, B=Z-cols from channel-major).
// Denominator: per-lane scalar accumulation + one shfl_xor(32) at the end.
// Block = 32 query rows, 4 waves = 4 m-quarters; merge partials in LDS.
// ---------------------------------------------------------------------------
__global__ __launch_bounds__(256) void attn_mfma(
    const __hip_bfloat16* __restrict__ qP, const __hip_bfloat16* __restrict__ kP,
    const __hip_bfloat16* __restrict__ vP,
    const __hip_bfloat16* __restrict__ qC, const __hip_bfloat16* __restrict__ kC,
    const __hip_bfloat16* __restrict__ vC,
    __hip_bfloat16* __restrict__ ctxPad)
{
  const int pass = blockIdx.y, b = blockIdx.z;
  const __hip_bfloat16 *XT, *YT, *ZD;
  if (pass == 0)      { XT = qP; YT = kP; ZD = vC; }
  else if (pass == 1) { XT = kP; YT = vP; ZD = qC; }
  else                { XT = vP; YT = qP; ZD = kC; }
  const size_t boff = (size_t)b * CCH * N_PIX;
  XT += boff; YT += boff; ZD += boff;
  __hip_bfloat16* __restrict__ ctx = ctxPad + ((size_t)(pass*BB + b))*PIX_P*32;

  const int t = threadIdx.x;
  const int wave = t >> 6, lane = t & 63;
  const int l31 = lane & 31, l5 = lane >> 5;
  const int n0 = blockIdx.x * 32;
  const int mbase = wave * (N_PIX/4);

  __shared__ float mgO[3][16][64];   // waves 1..3 partial O
  __shared__ float mgD[4][32];       // per-wave denominators by query i

  // GEMM1 B-frag (X): col = i = lane&31, k = c = l5*8 + e (two K=16 halves)
  const short8 bx0 = *(const short8*)&XT[(size_t)(n0 + l31)*CCH + l5*8];
  const short8 bx1 = *(const short8*)&XT[(size_t)(n0 + l31)*CCH + 16 + l5*8];

  f32x16 oacc = {0,0,0,0,0,0,0,0,0,0,0,0,0,0,0,0};
  float rs = 0.f;
  const float SC2 = 0.17677669529663687f * 1.4426950408889634f;  // 32^-0.5 * log2(e)
  const float OFF = 20.0f;

  for (int m0 = mbase; m0 < mbase + N_PIX/4; m0 += 32) {
    // GEMM1: A = Y rows (m = lane&31)
    const short8 ay0 = *(const short8*)&YT[(size_t)(m0 + l31)*CCH + l5*8];
    const short8 ay1 = *(const short8*)&YT[(size_t)(m0 + l31)*CCH + 16 + l5*8];
    f32x16 s = {0,0,0,0,0,0,0,0,0,0,0,0,0,0,0,0};
    s = __builtin_amdgcn_mfma_f32_32x32x16_bf16(ay0, bx0, s, 0, 0, 0);
    s = __builtin_amdgcn_mfma_f32_32x32x16_bf16(ay1, bx1, s, 0, 0, 0);

    // P = exp2(s*SC2 - OFF); per-lane denominator accumulation
    float p[16];
    #pragma unroll
    for (int r = 0; r < 16; ++r) { p[r] = exp2f(s[r]*SC2 - OFF); rs += p[r]; }

    // pack to bf16 pairs: w[rhi*2+j] = {m = 8*rhi + 4*l5 + 2j, +1}
    unsigned w[8];
    #pragma unroll
    for (int h = 0; h < 8; ++h) {
      const int rhi = h >> 1, j = h & 1;
      asm("v_cvt_pk_bf16_f32 %0, %1, %2"
          : "=v"(w[h]) : "v"(p[rhi*4 + 2*j]), "v"(p[rhi*4 + 2*j + 1]));
    }
    // lane<->lane+32 exchange: after swap(u=odd-rhi, v=even-rhi):
    //   u' = A-word t=2+j, v' = A-word t=j   (per K=16 block)
    asm("v_permlane32_swap_b32 %0, %1" : "+v"(w[2]), "+v"(w[0]));
    asm("v_permlane32_swap_b32 %0, %1" : "+v"(w[3]), "+v"(w[1]));
    asm("v_permlane32_swap_b32 %0, %1" : "+v"(w[6]), "+v"(w[4]));
    asm("v_permlane32_swap_b32 %0, %1" : "+v"(w[7]), "+v"(w[5]));
    union U { unsigned u[4]; short8 v8; };
    U A0, A1;
    A0.u[0] = w[0]; A0.u[1] = w[1]; A0.u[2] = w[2]; A0.u[3] = w[3];
    A1.u[0] = w[4]; A1.u[1] = w[5]; A1.u[2] = w[6]; A1.u[3] = w[7];

    // GEMM2: B = Z cols (c = lane&31, k = m-octet l5*8) from channel-major
    const short8 bz0 = *(const short8*)&ZD[(size_t)l31*N_PIX + m0 + l5*8];
    const short8 bz1 = *(const short8*)&ZD[(size_t)l31*N_PIX + m0 + 16 + l5*8];
    oacc = __builtin_amdgcn_mfma_f32_32x32x16_bf16(A0.v8, bz0, oacc, 0, 0, 0);
    oacc = __builtin_amdgcn_mfma_f32_32x32x16_bf16(A1.v8, bz1, oacc, 0, 0, 0);
  }

  // denominator: combine l5 halves -> full sum for query i = lane&31
  rs += __shfl_xor(rs, 32);
  if (l5 == 0) mgD[wave][l31] = rs;
  if (wave) {
    #pragma unroll
    for (int r = 0; r < 16; ++r) mgO[wave-1][r][lane] = oacc[r];
  }
  __syncthreads();
  if (wave == 0) {
    #pragma unroll
    for (int r = 0; r < 16; ++r) {
      const int i = (r & 3) + 8*(r >> 2) + 4*l5;
      const float den = mgD[0][i] + mgD[1][i] + mgD[2][i] + mgD[3][i];
      const float tot = oacc[r] + mgO[0][r][lane] + mgO[1][r][lane] + mgO[2][r][lane];
      const int pix = n0 + i;
      const int yy = pix >> 6, xx = pix & 63;
      ctx[((size_t)(yy+1)*66 + xx+1)*32 + l31] = __float2bfloat16(tot / den);
    }
  }
}

// ---------------------------------------------------------------------------
extern "C" void kernel_launch(void* const* d_in, const int* in_sizes, int n_in,
                              void* d_out, int out_size, void* d_ws, size_t ws_size,
                              hipStream_t stream)
{
  const float* x   = (const float*)d_in[0];
  const float* wq1 = (const float*)d_in[1];  const float* bq1 = (const float*)d_in[2];
  const float* wq2 = (const float*)d_in[3];  const float* bq2 = (const float*)d_in[4];
  const float* wk1 = (const float*)d_in[5];  const float* bk1 = (const float*)d_in[6];
  const float* wk2 = (const float*)d_in[7];  const float* bk2 = (const float*)d_in[8];
  const float* wv1 = (const float*)d_in[9];  const float* bv1 = (const float*)d_in[10];
  const float* wv2 = (const float*)d_in[11]; const float* bv2 = (const float*)d_in[12];
  const float* wr  = (const float*)d_in[13]; const float* br  = (const float*)d_in[14];
  const float* wg  = (const float*)d_in[15]; const float* bg  = (const float*)d_in[16];
  const float* wb_ = (const float*)d_in[17]; const float* bb_ = (const float*)d_in[18];
  const float* w2  = (const float*)d_in[19]; const float* b2  = (const float*)d_in[20];
  const float* w3  = (const float*)d_in[21]; const float* b3  = (const float*)d_in[22];

  // ---- workspace layout (bytes) ----
  char* base = (char*)d_ws;
  __hip_bfloat16* xcat  = (__hip_bfloat16*)(base + 0);        // [2][4356][96] padded
  __hip_bfloat16* q1p   = (__hip_bfloat16*)(base + 1672704);  // [3][2][4356][32] padded (later rgb)
  __hip_bfloat16* ctxP  = (__hip_bfloat16*)(base + 3345408);  // [3][2][4356][32] padded
  __hip_bfloat16* out4p = (__hip_bfloat16*)(base + 5018112);  // [2][4356][32] padded
  __hip_bfloat16* qkvP  = (__hip_bfloat16*)(base + 5575680);  // [3][2][4096][32]
  __hip_bfloat16* qkvC  = (__hip_bfloat16*)(base + 7148544);  // [3][2][32][4096]
  __hip_bfloat16* wbf   = (__hip_bfloat16*)(base + 8721408);  // 147456 elems
  const size_t PADSLOT = (size_t)BB*PIX_P*32;
  const size_t UPSLOT  = (size_t)BB*N_PIX*32;

  // zero all padded buffers (borders must be 0 every call)
  hipMemsetAsync(d_ws, 0, 5575680, stream);

  // weight convert/reorder + x padding
  WcvtPar wp;
  const float* wsrc[11] = {wq1,wk1,wv1,wq2,wk2,wv2,wr,wg,wb_,w2,w3};
  const int    wcin[11] = {64,64,64,32,32,32,32,32,32,96,32};
  const int    wdst[11] = {0,18432,36864,55296,64512,73728,82944,92160,101376,110592,138240};
  for (int i = 0; i < 11; ++i) { wp.src[i]=wsrc[i]; wp.cin[i]=wcin[i]; wp.dst[i]=wdst[i]; }
  wcvt_k<<<dim3(108, 11), dim3(256), 0, stream>>>(wp, wbf);
  xpad_k<<<dim3(64, BB), dim3(256), 0, stream>>>(x, xcat);

  // a1: xcat(ch 0..63) -> q1p/k1p/v1p (padded bf16)
  ConvPar c1 = {};
  for (int i = 0; i < 3; ++i) c1.in[i] = xcat;
  c1.wb[0]=wbf+0; c1.wb[1]=wbf+18432; c1.wb[2]=wbf+36864;
  c1.bias[0]=bq1; c1.bias[1]=bk1; c1.bias[2]=bv1;
  c1.outPad[0]=q1p; c1.outPad[1]=q1p+PADSLOT; c1.outPad[2]=q1p+2*PADSLOT;
  c1.mode = 1; c1.sch = 96;
  conv_mfma<64><<<dim3(64, 3, BB), dim3(256), 0, stream>>>(c1);

  // a2: q1p -> q/k/v in BOTH layouts
  ConvPar c2 = {};
  c2.in[0]=q1p; c2.in[1]=q1p+PADSLOT; c2.in[2]=q1p+2*PADSLOT;
  c2.wb[0]=wbf+55296; c2.wb[1]=wbf+64512; c2.wb[2]=wbf+73728;
  c2.bias[0]=bq2; c2.bias[1]=bk2; c2.bias[2]=bv2;
  c2.outPix[0]=qkvP; c2.outPix[1]=qkvP+UPSLOT; c2.outPix[2]=qkvP+2*UPSLOT;
  c2.outCh[0]=qkvC;  c2.outCh[1]=qkvC+UPSLOT;  c2.outCh[2]=qkvC+2*UPSLOT;
  c2.mode = 6; c2.sch = 32;
  conv_mfma<32><<<dim3(64, 3, BB), dim3(256), 0, stream>>>(c2);

  // attention: 3 passes x 2 batches -> ctxP (padded bf16)
  attn_mfma<<<dim3(N_PIX/32, 3, BB), dim3(256), 0, stream>>>(
      qkvP, qkvP+UPSLOT, qkvP+2*UPSLOT, qkvC, qkvC+UPSLOT, qkvC+2*UPSLOT, ctxP);

  // a3: ctxP -> r/g/b (unpadded bf16 pixel-major, overlaid on q1p region)
  __hip_bfloat16* rgb = q1p;
  ConvPar c3 = {};
  c3.in[0]=ctxP; c3.in[1]=ctxP+PADSLOT; c3.in[2]=ctxP+2*PADSLOT;
  c3.wb[0]=wbf+82944; c3.wb[1]=wbf+92160; c3.wb[2]=wbf+101376;
  c3.bias[0]=br; c3.bias[1]=bg; c3.bias[2]=bb_;
  c3.outPix[0]=rgb; c3.outPix[1]=rgb+UPSLOT; c3.outPix[2]=rgb+2*UPSLOT;
  c3.mode = 2; c3.sch = 32;
  conv_mfma<32><<<dim3(64, 3, BB), dim3(256), 0, stream>>>(c3);

  // ctx average -> xcat channels 64..95
  avg3_k<<<dim3(64, BB), dim3(256), 0, stream>>>(rgb, rgb+UPSLOT, rgb+2*UPSLOT, xcat);

  // a4: xcat (96 ch) -> out4p (padded bf16)
  ConvPar c4 = {};
  c4.in[0]=xcat; c4.wb[0]=wbf+110592; c4.bias[0]=b2;
  c4.outPad[0]=out4p; c4.mode = 1; c4.sch = 96;
  conv_mfma<96><<<dim3(64, 1, BB), dim3(256), 0, stream>>>(c4);

  // a5: out4p -> d_out (fp32 NCHW)
  ConvPar c5 = {};
  c5.in[0]=out4p; c5.wb[0]=wbf+138240; c5.bias[0]=b3;
  c5.outF[0]=(float*)d_out; c5.mode = 8; c5.sch = 32;
  conv_mfma<32><<<dim3(64, 1, BB), dim3(256), 0, stream>>>(c5);
}

// Round 9
// 101.571 us; speedup vs baseline: 3.8645x; 1.0840x over previous
//
#include <hip/hip_runtime.h>
#include <hip/hip_bf16.h>
#include <math.h>

#define N_PIX 4096
#define CCH 32
#define BB 2
#define PIX_P 4356   // 66*66 padded pixel grid

typedef __attribute__((ext_vector_type(8))) short short8;
typedef __attribute__((ext_vector_type(4))) float f32x4;
typedef __attribute__((ext_vector_type(16))) float f32x16;

// ---------------------------------------------------------------------------
// Weight convert/reorder: fp32 [co][cin][3][3] -> bf16 [co][kk][ci]
// ---------------------------------------------------------------------------
struct WcvtPar {
  const float* src[11];
  int cin[11];
  int dst[11];     // element offset into wbf arena
};

__global__ __launch_bounds__(256) void wcvt_k(WcvtPar p, __hip_bfloat16* __restrict__ wbf)
{
  const int s = blockIdx.y;
  const int cin = p.cin[s];
  const int K = 9*cin;
  const int total = 32*K;
  const float* __restrict__ src = p.src[s];
  __hip_bfloat16* __restrict__ dst = wbf + p.dst[s];
  for (int j = blockIdx.x*256 + threadIdx.x; j < total; j += gridDim.x*256) {
    int co = j / K, k = j - co*K;
    int kk = k / cin, ci = k - kk*cin;
    dst[j] = __float2bfloat16(src[(size_t)(co*cin + ci)*9 + kk]);
  }
}

// ---------------------------------------------------------------------------
// Border-zero: zero the 260 border pixels of each padded slot (interiors are
// fully overwritten every call). Replaces the 5.5 MB memset.
// ---------------------------------------------------------------------------
struct BzPar { __hip_bfloat16* p[16]; int sch[16]; };

__global__ __launch_bounds__(256) void bzero_k(BzPar bp)
{
  const int s = blockIdx.x;
  const int sch = bp.sch[s];
  __hip_bfloat16* __restrict__ ptr = bp.p[s];
  const int total = 260*sch;
  for (int j = threadIdx.x; j < total; j += 256) {
    int e = j / sch, c = j - e*sch;
    int yy, xx;
    if (e < 66)       { yy = 0;       xx = e; }
    else if (e < 132) { yy = 65;      xx = e - 66; }
    else if (e < 196) { yy = e - 131; xx = 0; }     // rows 1..64
    else              { yy = e - 195; xx = 65; }
    ptr[((size_t)yy*66 + xx)*sch + c] = __float2bfloat16(0.f);
  }
}

// ---------------------------------------------------------------------------
// x fp32 NCHW -> bf16 padded pixel-major xcat[b][66*66][96], channels 0..63.
// ---------------------------------------------------------------------------
__global__ __launch_bounds__(256) void xpad_k(const float* __restrict__ x,
                                              __hip_bfloat16* __restrict__ xcat)
{
  const int y = blockIdx.x, b = blockIdx.y;
  const int t = threadIdx.x;
  for (int j = t; j < 4096; j += 256) {
    int ci = j >> 6, xx = j & 63;
    float v = x[((size_t)(b*64 + ci)*64 + y)*64 + xx];
    xcat[((size_t)b*PIX_P + (size_t)(y+1)*66 + xx+1)*96 + ci] = __float2bfloat16(v);
  }
}

// ---------------------------------------------------------------------------
// avg3: ctx = (r+g+b)/3 -> xcat channels 64..95 (padded interior).
// ---------------------------------------------------------------------------
__global__ __launch_bounds__(256) void avg3_k(
    const __hip_bfloat16* __restrict__ r, const __hip_bfloat16* __restrict__ g,
    const __hip_bfloat16* __restrict__ bl, __hip_bfloat16* __restrict__ xcat)
{
  const int y = blockIdx.x, b = blockIdx.y;
  const int t = threadIdx.x;
  for (int j = t; j < 64*32; j += 256) {
    int xx = j >> 5, c = j & 31;
    size_t src = ((size_t)b*N_PIX + y*64 + xx)*32 + c;
    float v = (__bfloat162float(r[src]) + __bfloat162float(g[src]) +
               __bfloat162float(bl[src])) * (1.0f/3.0f);
    xcat[((size_t)b*PIX_P + (size_t)(y+1)*66 + xx+1)*96 + 64 + c] = __float2bfloat16(v);
  }
}

// ---------------------------------------------------------------------------
// MFMA implicit-GEMM 3x3 conv + bias + ReLU. 2 waves/block, 32 px/block:
// blockIdx.x = row*2 + half; wave covers 16 px. Better CU balance than the
// 4-wave version (a4/a5 were 0.5 blocks/CU).
// ---------------------------------------------------------------------------
struct ConvPar {
  const __hip_bfloat16* in[3];
  const __hip_bfloat16* wb[3];
  const float* bias[3];
  __hip_bfloat16* outPad[3];
  __hip_bfloat16* outPix[3];
  __hip_bfloat16* outCh[3];
  float* outF[3];
  int mode, sch;
};

template<int CIN>
__global__ __launch_bounds__(128) void conv_mfma(ConvPar p)
{
  constexpr int K = 9*CIN;
  const int sel = blockIdx.y, b = blockIdx.z;
  const int sch = p.sch;
  const __hip_bfloat16* __restrict__ in = p.in[sel] + (size_t)b*PIX_P*sch;
  const __hip_bfloat16* __restrict__ wb = p.wb[sel];
  const float* __restrict__ bias = p.bias[sel];
  const int t = threadIdx.x, wave = t >> 6, lane = t & 63;
  const int l15 = lane & 15, q4 = lane >> 4;
  const int y = blockIdx.x >> 1;
  const int xw = (blockIdx.x & 1)*32 + wave*16;

  f32x4 acc0 = {0.f,0.f,0.f,0.f}, acc1 = {0.f,0.f,0.f,0.f};
  #pragma unroll
  for (int ks = 0; ks < K/32; ++ks) {
    const int kk  = (ks*32)/CIN;
    const int ci0 = (ks*32)%CIN + q4*8;
    const int dy = kk/3 - 1, dx = (kk%3) - 1;
    const short8 bw0 = *(const short8*)&wb[(size_t)l15*K      + ks*32 + q4*8];
    const short8 bw1 = *(const short8*)&wb[(size_t)(16+l15)*K + ks*32 + q4*8];
    const short8 av  = *(const short8*)&in[((size_t)(y+1+dy)*66 + xw + l15 + 1 + dx)*sch + ci0];
    acc0 = __builtin_amdgcn_mfma_f32_16x16x32_bf16(av, bw0, acc0, 0, 0, 0);
    acc1 = __builtin_amdgcn_mfma_f32_16x16x32_bf16(av, bw1, acc1, 0, 0, 0);
  }
  const float bz0 = bias[l15], bz1 = bias[16 + l15];
  #pragma unroll
  for (int r = 0; r < 4; ++r) {
    const int xx = xw + q4*4 + r;
    const int pix = y*64 + xx;
    const float v0 = fmaxf(acc0[r] + bz0, 0.f);
    const float v1 = fmaxf(acc1[r] + bz1, 0.f);
    if (p.mode & 1) {
      __hip_bfloat16* o = p.outPad[sel] + ((size_t)b*PIX_P + (size_t)(y+1)*66 + xx+1)*32;
      o[l15] = __float2bfloat16(v0); o[16+l15] = __float2bfloat16(v1);
    }
    if (p.mode & 2) {
      __hip_bfloat16* o = p.outPix[sel] + ((size_t)b*N_PIX + pix)*32;
      o[l15] = __float2bfloat16(v0); o[16+l15] = __float2bfloat16(v1);
    }
    if (p.mode & 4) {
      __hip_bfloat16* o = p.outCh[sel] + (size_t)b*32*N_PIX + pix;
      o[(size_t)l15*N_PIX]      = __float2bfloat16(v0);
      o[(size_t)(16+l15)*N_PIX] = __float2bfloat16(v1);
    }
    if (p.mode & 8) {
      float* o = p.outF[sel] + (size_t)b*32*N_PIX + pix;
      o[(size_t)l15*N_PIX]      = v0;
      o[(size_t)(16+l15)*N_PIX] = v1;
    }
  }
}

// ---------------------------------------------------------------------------
// Attention pass, 32x32x16 MFMA, in-register P (verified R8).
// Now 8 waves/block (512 thr), each wave 1/8 of m (512 keys) -> 24 waves/CU.
// rs accumulation split into 4 partials to break the serial add chain.
// ---------------------------------------------------------------------------
__global__ __launch_bounds__(512) void attn_mfma(
    const __hip_bfloat16* __restrict__ qP, const __hip_bfloat16* __restrict__ kP,
    const __hip_bfloat16* __restrict__ vP,
    const __hip_bfloat16* __restrict__ qC, const __hip_bfloat16* __restrict__ kC,
    const __hip_bfloat16* __restrict__ vC,
    __hip_bfloat16* __restrict__ ctxPad)
{
  const int pass = blockIdx.y, b = blockIdx.z;
  const __hip_bfloat16 *XT, *YT, *ZD;
  if (pass == 0)      { XT = qP; YT = kP; ZD = vC; }
  else if (pass == 1) { XT = kP; YT = vP; ZD = qC; }
  else                { XT = vP; YT = qP; ZD = kC; }
  const size_t boff = (size_t)b * CCH * N_PIX;
  XT += boff; YT += boff; ZD += boff;
  __hip_bfloat16* __restrict__ ctx = ctxPad + ((size_t)(pass*BB + b))*PIX_P*32;

  const int t = threadIdx.x;
  const int wave = t >> 6, lane = t & 63;
  const int l31 = lane & 31, l5 = lane >> 5;
  const int n0 = blockIdx.x * 32;
  const int mbase = wave * (N_PIX/8);

  __shared__ float mgO[7][16][64];   // waves 1..7 partial O
  __shared__ float mgD[8][32];       // per-wave denominators by query i

  // GEMM1 B-frag (X): col = i = lane&31, k = c = l5*8 + e (two K=16 halves)
  const short8 bx0 = *(const short8*)&XT[(size_t)(n0 + l31)*CCH + l5*8];
  const short8 bx1 = *(const short8*)&XT[(size_t)(n0 + l31)*CCH + 16 + l5*8];

  f32x16 oacc = {0,0,0,0,0,0,0,0,0,0,0,0,0,0,0,0};
  float rs0 = 0.f, rs1 = 0.f, rs2 = 0.f, rs3 = 0.f;
  const float SC2 = 0.17677669529663687f * 1.4426950408889634f;  // 32^-0.5 * log2(e)
  const float OFF = 20.0f;

  for (int m0 = mbase; m0 < mbase + N_PIX/8; m0 += 32) {
    // GEMM1: A = Y rows (m = lane&31)
    const short8 ay0 = *(const short8*)&YT[(size_t)(m0 + l31)*CCH + l5*8];
    const short8 ay1 = *(const short8*)&YT[(size_t)(m0 + l31)*CCH + 16 + l5*8];
    f32x16 s = {0,0,0,0,0,0,0,0,0,0,0,0,0,0,0,0};
    s = __builtin_amdgcn_mfma_f32_32x32x16_bf16(ay0, bx0, s, 0, 0, 0);
    s = __builtin_amdgcn_mfma_f32_32x32x16_bf16(ay1, bx1, s, 0, 0, 0);

    // P = exp2(s*SC2 - OFF); 4 partial denominator accumulators
    float p[16];
    #pragma unroll
    for (int r = 0; r < 16; ++r) p[r] = exp2f(s[r]*SC2 - OFF);
    #pragma unroll
    for (int r = 0; r < 4; ++r) {
      rs0 += p[r];
      rs1 += p[4 + r];
      rs2 += p[8 + r];
      rs3 += p[12 + r];
    }

    // pack to bf16 pairs: w[rhi*2+j] = {m = 8*rhi + 4*l5 + 2j, +1}
    unsigned w[8];
    #pragma unroll
    for (int h = 0; h < 8; ++h) {
      const int rhi = h >> 1, j = h & 1;
      asm("v_cvt_pk_bf16_f32 %0, %1, %2"
          : "=v"(w[h]) : "v"(p[rhi*4 + 2*j]), "v"(p[rhi*4 + 2*j + 1]));
    }
    // lane<->lane+32 exchange -> GEMM2 A-fragments in-register
    asm("v_permlane32_swap_b32 %0, %1" : "+v"(w[2]), "+v"(w[0]));
    asm("v_permlane32_swap_b32 %0, %1" : "+v"(w[3]), "+v"(w[1]));
    asm("v_permlane32_swap_b32 %0, %1" : "+v"(w[6]), "+v"(w[4]));
    asm("v_permlane32_swap_b32 %0, %1" : "+v"(w[7]), "+v"(w[5]));
    union U { unsigned u[4]; short8 v8; };
    U A0, A1;
    A0.u[0] = w[0]; A0.u[1] = w[1]; A0.u[2] = w[2]; A0.u[3] = w[3];
    A1.u[0] = w[4]; A1.u[1] = w[5]; A1.u[2] = w[6]; A1.u[3] = w[7];

    // GEMM2: B = Z cols (c = lane&31, k = m-octet l5*8) from channel-major
    const short8 bz0 = *(const short8*)&ZD[(size_t)l31*N_PIX + m0 + l5*8];
    const short8 bz1 = *(const short8*)&ZD[(size_t)l31*N_PIX + m0 + 16 + l5*8];
    oacc = __builtin_amdgcn_mfma_f32_32x32x16_bf16(A0.v8, bz0, oacc, 0, 0, 0);
    oacc = __builtin_amdgcn_mfma_f32_32x32x16_bf16(A1.v8, bz1, oacc, 0, 0, 0);
  }

  // denominator: combine partials + l5 halves -> full sum for query i
  float rs = (rs0 + rs1) + (rs2 + rs3);
  rs += __shfl_xor(rs, 32);
  if (l5 == 0) mgD[wave][l31] = rs;
  if (wave) {
    #pragma unroll
    for (int r = 0; r < 16; ++r) mgO[wave-1][r][lane] = oacc[r];
  }
  __syncthreads();
  if (wave == 0) {
    #pragma unroll
    for (int r = 0; r < 16; ++r) {
      const int i = (r & 3) + 8*(r >> 2) + 4*l5;
      float den = 0.f, tot = oacc[r];
      #pragma unroll
      for (int ww = 0; ww < 8; ++ww) den += mgD[ww][i];
      #pragma unroll
      for (int ww = 0; ww < 7; ++ww) tot += mgO[ww][r][lane];
      const int pix = n0 + i;
      const int yy = pix >> 6, xx = pix & 63;
      ctx[((size_t)(yy+1)*66 + xx+1)*32 + l31] = __float2bfloat16(tot / den);
    }
  }
}

// ---------------------------------------------------------------------------
extern "C" void kernel_launch(void* const* d_in, const int* in_sizes, int n_in,
                              void* d_out, int out_size, void* d_ws, size_t ws_size,
                              hipStream_t stream)
{
  const float* x   = (const float*)d_in[0];
  const float* wq1 = (const float*)d_in[1];  const float* bq1 = (const float*)d_in[2];
  const float* wq2 = (const float*)d_in[3];  const float* bq2 = (const float*)d_in[4];
  const float* wk1 = (const float*)d_in[5];  const float* bk1 = (const float*)d_in[6];
  const float* wk2 = (const float*)d_in[7];  const float* bk2 = (const float*)d_in[8];
  const float* wv1 = (const float*)d_in[9];  const float* bv1 = (const float*)d_in[10];
  const float* wv2 = (const float*)d_in[11]; const float* bv2 = (const float*)d_in[12];
  const float* wr  = (const float*)d_in[13]; const float* br  = (const float*)d_in[14];
  const float* wg  = (const float*)d_in[15]; const float* bg  = (const float*)d_in[16];
  const float* wb_ = (const float*)d_in[17]; const float* bb_ = (const float*)d_in[18];
  const float* w2  = (const float*)d_in[19]; const float* b2  = (const float*)d_in[20];
  const float* w3  = (const float*)d_in[21]; const float* b3  = (const float*)d_in[22];

  // ---- workspace layout (bytes) ----
  char* base = (char*)d_ws;
  __hip_bfloat16* xcat  = (__hip_bfloat16*)(base + 0);        // [2][4356][96] padded
  __hip_bfloat16* q1p   = (__hip_bfloat16*)(base + 1672704);  // [3][2][4356][32] padded (later rgb)
  __hip_bfloat16* ctxP  = (__hip_bfloat16*)(base + 3345408);  // [3][2][4356][32] padded
  __hip_bfloat16* out4p = (__hip_bfloat16*)(base + 5018112);  // [2][4356][32] padded
  __hip_bfloat16* qkvP  = (__hip_bfloat16*)(base + 5575680);  // [3][2][4096][32]
  __hip_bfloat16* qkvC  = (__hip_bfloat16*)(base + 7148544);  // [3][2][32][4096]
  __hip_bfloat16* wbf   = (__hip_bfloat16*)(base + 8721408);  // 147456 elems
  const size_t PADSLOT = (size_t)BB*PIX_P*32;
  const size_t UPSLOT  = (size_t)BB*N_PIX*32;

  // border zeros for all padded slots (interiors fully overwritten per call)
  BzPar bz;
  for (int i = 0; i < 2; ++i)  { bz.p[i]      = xcat  + (size_t)i*PIX_P*96; bz.sch[i]      = 96; }
  for (int i = 0; i < 6; ++i)  { bz.p[2+i]    = q1p   + (size_t)i*PIX_P*32; bz.sch[2+i]    = 32; }
  for (int i = 0; i < 6; ++i)  { bz.p[8+i]    = ctxP  + (size_t)i*PIX_P*32; bz.sch[8+i]    = 32; }
  for (int i = 0; i < 2; ++i)  { bz.p[14+i]   = out4p + (size_t)i*PIX_P*32; bz.sch[14+i]   = 32; }
  bzero_k<<<dim3(16), dim3(256), 0, stream>>>(bz);

  // weight convert/reorder + x padding
  WcvtPar wp;
  const float* wsrc[11] = {wq1,wk1,wv1,wq2,wk2,wv2,wr,wg,wb_,w2,w3};
  const int    wcin[11] = {64,64,64,32,32,32,32,32,32,96,32};
  const int    wdst[11] = {0,18432,36864,55296,64512,73728,82944,92160,101376,110592,138240};
  for (int i = 0; i < 11; ++i) { wp.src[i]=wsrc[i]; wp.cin[i]=wcin[i]; wp.dst[i]=wdst[i]; }
  wcvt_k<<<dim3(54, 11), dim3(256), 0, stream>>>(wp, wbf);
  xpad_k<<<dim3(64, BB), dim3(256), 0, stream>>>(x, xcat);

  // a1: xcat(ch 0..63) -> q1p/k1p/v1p (padded bf16)
  ConvPar c1 = {};
  for (int i = 0; i < 3; ++i) c1.in[i] = xcat;
  c1.wb[0]=wbf+0; c1.wb[1]=wbf+18432; c1.wb[2]=wbf+36864;
  c1.bias[0]=bq1; c1.bias[1]=bk1; c1.bias[2]=bv1;
  c1.outPad[0]=q1p; c1.outPad[1]=q1p+PADSLOT; c1.outPad[2]=q1p+2*PADSLOT;
  c1.mode = 1; c1.sch = 96;
  conv_mfma<64><<<dim3(128, 3, BB), dim3(128), 0, stream>>>(c1);

  // a2: q1p -> q/k/v in BOTH layouts
  ConvPar c2 = {};
  c2.in[0]=q1p; c2.in[1]=q1p+PADSLOT; c2.in[2]=q1p+2*PADSLOT;
  c2.wb[0]=wbf+55296; c2.wb[1]=wbf+64512; c2.wb[2]=wbf+73728;
  c2.bias[0]=bq2; c2.bias[1]=bk2; c2.bias[2]=bv2;
  c2.outPix[0]=qkvP; c2.outPix[1]=qkvP+UPSLOT; c2.outPix[2]=qkvP+2*UPSLOT;
  c2.outCh[0]=qkvC;  c2.outCh[1]=qkvC+UPSLOT;  c2.outCh[2]=qkvC+2*UPSLOT;
  c2.mode = 6; c2.sch = 32;
  conv_mfma<32><<<dim3(128, 3, BB), dim3(128), 0, stream>>>(c2);

  // attention: 3 passes x 2 batches -> ctxP (padded bf16)
  attn_mfma<<<dim3(N_PIX/32, 3, BB), dim3(512), 0, stream>>>(
      qkvP, qkvP+UPSLOT, qkvP+2*UPSLOT, qkvC, qkvC+UPSLOT, qkvC+2*UPSLOT, ctxP);

  // a3: ctxP -> r/g/b (unpadded bf16 pixel-major, overlaid on q1p region)
  __hip_bfloat16* rgb = q1p;
  ConvPar c3 = {};
  c3.in[0]=ctxP; c3.in[1]=ctxP+PADSLOT; c3.in[2]=ctxP+2*PADSLOT;
  c3.wb[0]=wbf+82944; c3.wb[1]=wbf+92160; c3.wb[2]=wbf+101376;
  c3.bias[0]=br; c3.bias[1]=bg; c3.bias[2]=bb_;
  c3.outPix[0]=rgb; c3.outPix[1]=rgb+UPSLOT; c3.outPix[2]=rgb+2*UPSLOT;
  c3.mode = 2; c3.sch = 32;
  conv_mfma<32><<<dim3(128, 3, BB), dim3(128), 0, stream>>>(c3);

  // ctx average -> xcat channels 64..95
  avg3_k<<<dim3(64, BB), dim3(256), 0, stream>>>(rgb, rgb+UPSLOT, rgb+2*UPSLOT, xcat);

  // a4: xcat (96 ch) -> out4p (padded bf16)
  ConvPar c4 = {};
  c4.in[0]=xcat; c4.wb[0]=wbf+110592; c4.bias[0]=b2;
  c4.outPad[0]=out4p; c4.mode = 1; c4.sch = 96;
  conv_mfma<96><<<dim3(128, 1, BB), dim3(128), 0, stream>>>(c4);

  // a5: out4p -> d_out (fp32 NCHW)
  ConvPar c5 = {};
  c5.in[0]=out4p; c5.wb[0]=wbf+138240; c5.bias[0]=b3;
  c5.outF[0]=(float*)d_out; c5.mode = 8; c5.sch = 32;
  conv_mfma<32><<<dim3(128, 1, BB), dim3(128), 0, stream>>>(c5);
}